// Round 8
// baseline (62.719 us; speedup 1.0000x reference)
//
#include <hip/hip_runtime.h>

// AttnMap, fully fused (algebra verified rounds 1-7):
//   M[f][ch] = sum_q dec[b, q*16+t, ch] * W[q*8 + (ch>>5)][f]
//   out[bt][s][f] = relu( sum_ch enc[bt][s][ch] * M[f][ch] + bias[f] )
// Block = (bt, fq, rh): 512 rows x 64 f. 4 waves, each 128 rows.
// R8: wave-private E-tile widened to [32][64] (two k-chunks resident,
// ping-pong halves), 4-deep register GLOAD pipeline, full 8-slot row-XOR
// swizzle. LDS 48KB -> 3 blocks/CU.

#define CCH 256
#define FF  256
#define HW  1024

typedef __bf16 bf16x8 __attribute__((ext_vector_type(8)));
typedef float  f32x4  __attribute__((ext_vector_type(4)));
typedef float  f32x16 __attribute__((ext_vector_type(16)));
typedef unsigned short u16x4 __attribute__((ext_vector_type(4)));
typedef unsigned short u16x8 __attribute__((ext_vector_type(8)));

__device__ __forceinline__ unsigned short f2bf(float f) {
    __bf16 b = (__bf16)f;
    return __builtin_bit_cast(unsigned short, b);
}

__global__ __launch_bounds__(256, 3) void attnmap_fused(
        const float* __restrict__ dec, const float* __restrict__ E,
        const float* __restrict__ W,  const float* __restrict__ bias,
        float* __restrict__ O) {
    const int id0 = blockIdx.x;                      // 0..1023
    const int id  = ((id0 & 7) << 7) | (id0 >> 3);   // XCD-chunked bijection
    const int bt = id >> 3;
    const int fq = (id >> 1) & 3;                    // 64-f slice
    const int rh = id & 1;                           // 512-row half
    const int tid = threadIdx.x;
    const int lane = tid & 63, wq = tid >> 6;
    const int lr5 = lane & 31, kgr = lane >> 5;

    __shared__ unsigned short Bs[64 * 256];          // 32 KB M-slice, swizzled
    __shared__ unsigned short Et[4][32 * 64];        // 4 x 4KB wave-private tiles

    // ---------------- prologue: compute M[64f][256ch] into Bs ----------------
    {
        float* dstg = (float*)&Et[0][0];             // 2 KB staging [16 q][32 ch]
        const float* decb = dec + (size_t)(bt >> 4) * 65536 + (size_t)(bt & 15) * 256;
        const int fl = tid & 63, sc = tid >> 6;      // f-local, ch-subgroup
        for (int g = 0; g < 8; ++g) {
            if (tid < 128) {
                const int q = tid >> 3, seg = tid & 7;
                *reinterpret_cast<f32x4*>(&dstg[q * 32 + seg * 4]) =
                    *reinterpret_cast<const f32x4*>(decb + q * 4096 + g * 32 + seg * 4);
            }
            __syncthreads();
            float s[8];
            #pragma unroll
            for (int e = 0; e < 8; ++e) s[e] = 0.f;
            #pragma unroll
            for (int q = 0; q < 16; ++q) {
                const float w = W[(q * 8 + g) * FF + fq * 64 + fl];   // coalesced
                #pragma unroll
                for (int e = 0; e < 8; ++e) s[e] += dstg[q * 32 + sc * 8 + e] * w;
            }
            u16x8 m8;
            #pragma unroll
            for (int e = 0; e < 8; ++e) m8[e] = f2bf(s[e]);
            *reinterpret_cast<u16x8*>(&Bs[fl * 256 + ((g * 4 + sc) ^ (fl & 7)) * 8]) = m8;
            __syncthreads();
        }
    }

    // ---------------- main loop: 128 rows/wave = 4 chunks x 8 k-steps ----------------
    const float* Ebt = E + (size_t)bt * (HW * CCH);
    float*       Obt = O + (size_t)bt * (HW * FF);
    const int rowbase = rh * 512 + wq * 128;
    unsigned short* Etw = &Et[wq][0];

    const float bv0 = bias[fq * 64 + lr5];
    const float bv1 = bias[fq * 64 + 32 + lr5];

    const int g_r8 = lane >> 3;                      // staging row-in-8
    const int g_s3 = lane & 7;                       // staging quad slot
    const int bswz = lr5 & 7;                        // Bs read swizzle
    const int eswz = lr5 & 7;                        // E-tile read swizzle (8-slot)
    const unsigned short* Bs0 = &Bs[lr5 * 256];
    const unsigned short* Bs1 = &Bs[(32 + lr5) * 256];
    const unsigned short* Etr = &Etw[lr5 * 64];

    f32x16 acc0, acc1;

    auto GLOAD = [&](int it, f32x4 (&S)[4]) {        // full 128B-line loads
        const float* base = Ebt + (size_t)(rowbase + (it >> 3) * 32) * CCH
                          + (it & 7) * 32 + g_s3 * 4;
        #pragma unroll
        for (int i = 0; i < 4; ++i)
            S[i] = *reinterpret_cast<const f32x4*>(base + (size_t)(i * 8 + g_r8) * CCH);
    };
    auto EWRITE = [&](int it, const f32x4 (&S)[4]) { // cvt + swizzled ds_write_b64
        const int p = it & 1;
        #pragma unroll
        for (int i = 0; i < 4; ++i) {
            const int r = i * 8 + g_r8;
            u16x4 h = { f2bf(S[i][0]), f2bf(S[i][1]), f2bf(S[i][2]), f2bf(S[i][3]) };
            const int slot = (p * 4 + (g_s3 >> 1)) ^ (r & 7);
            *reinterpret_cast<u16x4*>(&Etw[r * 64 + slot * 8 + (g_s3 & 1) * 4]) = h;
        }
    };
    auto COMPUTE = [&](int it) {
        const int p = it & 1, kc = it & 7;
        if (kc == 0) { acc0 = (f32x16)0.f; acc1 = (f32x16)0.f; }
        #pragma unroll
        for (int kk = 0; kk < 2; ++kk) {
            const bf16x8 af = *reinterpret_cast<const bf16x8*>(
                &Etr[((p * 4 + kk * 2 + kgr) ^ eswz) * 8]);
            const bf16x8 b0 = *reinterpret_cast<const bf16x8*>(
                &Bs0[((kc * 4 + kk * 2 + kgr) ^ bswz) * 8]);
            const bf16x8 b1 = *reinterpret_cast<const bf16x8*>(
                &Bs1[((kc * 4 + kk * 2 + kgr) ^ bswz) * 8]);
            acc0 = __builtin_amdgcn_mfma_f32_32x32x16_bf16(af, b0, acc0, 0, 0, 0);
            acc1 = __builtin_amdgcn_mfma_f32_32x32x16_bf16(af, b1, acc1, 0, 0, 0);
        }
        if (kc == 7) {
            // C/D: col = lane&31, row = (reg&3) + 8*(reg>>2) + 4*(lane>>5)
            const int row0 = rowbase + (it >> 3) * 32 + 4 * kgr;
            #pragma unroll
            for (int reg = 0; reg < 16; ++reg) {
                const int r = row0 + (reg & 3) + 8 * (reg >> 2);
                float* op = Obt + (size_t)r * FF + fq * 64 + lr5;
                __builtin_nontemporal_store(fmaxf(acc0[reg] + bv0, 0.f), op);
                __builtin_nontemporal_store(fmaxf(acc1[reg] + bv1, 0.f), op + 32);
            }
        }
    };

    f32x4 SA[4], SB[4], SC[4], SD[4];                // named 4-deep pipeline
    GLOAD(0, SA); GLOAD(1, SB); GLOAD(2, SC); GLOAD(3, SD);
    EWRITE(0, SA); EWRITE(1, SB);
    for (int it4 = 0; it4 < 32; it4 += 4) {
        COMPUTE(it4 + 0);
        if (it4 + 4 < 32) GLOAD(it4 + 4, SA);
        EWRITE(it4 + 2, SC);
        COMPUTE(it4 + 1);
        if (it4 + 5 < 32) GLOAD(it4 + 5, SB);
        EWRITE(it4 + 3, SD);
        COMPUTE(it4 + 2);
        if (it4 + 6 < 32) GLOAD(it4 + 6, SC);
        if (it4 + 4 < 32) EWRITE(it4 + 4, SA);
        COMPUTE(it4 + 3);
        if (it4 + 7 < 32) GLOAD(it4 + 7, SD);
        if (it4 + 5 < 32) EWRITE(it4 + 5, SB);
    }
}

extern "C" void kernel_launch(void* const* d_in, const int* in_sizes, int n_in,
                              void* d_out, int out_size, void* d_ws, size_t ws_size,
                              hipStream_t stream) {
    const float* dec  = (const float*)d_in[0];   // (8, 256, 256)
    const float* enc  = (const float*)d_in[1];   // (8, 16, 32, 32, 256)
    const float* W    = (const float*)d_in[2];   // (128, 256)
    const float* bias = (const float*)d_in[3];   // (256,)
    float* out = (float*)d_out;                  // (8, 16, 32, 32, 256) fp32

    attnmap_fused<<<dim3(1024), dim3(256), 0, stream>>>(dec, enc, W, bias, out);
}

// Round 9
// 61.214 us; speedup vs baseline: 1.0246x; 1.0246x over previous
//
#include <hip/hip_runtime.h>

// AttnMap (algebra verified rounds 1-8):
//   Mt[bt][f][ch] = sum_q dec[b, q*16+t, ch] * W[q*8 + (ch>>5)][f]
//   out[bt][s][f] = relu( sum_ch enc[bt][s][ch] * Mt[f][ch] + bias[f] )
// R9: Mt precomputed once (kernel 1, verified R5). GEMM blocks = 128 rows x
// 64 f (bt x 4 fq x 8 rowgroups = 4096 blocks) so the per-XCD live set is
// ~4 bt = 4MB = L2; Bs staged via global_load_lds(16B) with source-side XOR
// (linear LDS dest), 1 barrier. Main loop / swizzles / epilogue = R7 verbatim.
// LDS 40KB -> 4 blocks/CU.

#define CCH 256
#define FF  256
#define HW  1024

typedef __bf16 bf16x8 __attribute__((ext_vector_type(8)));
typedef float  f32x4  __attribute__((ext_vector_type(4)));
typedef float  f32x16 __attribute__((ext_vector_type(16)));
typedef unsigned short u16x4 __attribute__((ext_vector_type(4)));
typedef unsigned short u16x8 __attribute__((ext_vector_type(8)));

__device__ __forceinline__ unsigned short f2bf(float f) {
    __bf16 b = (__bf16)f;
    return __builtin_bit_cast(unsigned short, b);
}

__device__ __forceinline__ void gload_lds16(const unsigned short* g, unsigned short* l) {
    __builtin_amdgcn_global_load_lds(
        (const __attribute__((address_space(1))) unsigned int*)g,
        (__attribute__((address_space(3))) unsigned int*)l, 16, 0, 0);
}

// ---------------- Phase 1: Mt[bt][f][ch] (bf16, f-major) — verified R5 ----------------
__global__ __launch_bounds__(256) void compute_Mt_kernel(
        const float* __restrict__ dec, const float* __restrict__ W,
        unsigned short* __restrict__ Mt) {
    const int j  = blockIdx.x;            // g-pair: g = 2j, 2j+1
    const int bt = blockIdx.y;
    const int b  = bt >> 4, t = bt & 15;
    const int f  = threadIdx.x;
    __shared__ float ldec[16][64];        // 16 q x 64 ch (this g-pair)

    const float* decbt = dec + (size_t)b * 65536 + (size_t)t * 256 + j * 64;
    {
        const int q = threadIdx.x >> 4, seg = threadIdx.x & 15;
        const float4 v = *reinterpret_cast<const float4*>(decbt + q * 4096 + seg * 4);
        *reinterpret_cast<float4*>(&ldec[q][seg * 4]) = v;
    }
    __syncthreads();

    u16x8 rv[8];
    #pragma unroll
    for (int gi = 0; gi < 2; ++gi) {
        const int g = j * 2 + gi;
        float wv[16];
        #pragma unroll
        for (int q = 0; q < 16; ++q) wv[q] = W[(q * 8 + g) * FF + f];   // coalesced
        #pragma unroll
        for (int cc = 0; cc < 32; ++cc) {
            float s = 0.f;
            #pragma unroll
            for (int q = 0; q < 16; ++q) s += ldec[q][gi * 32 + cc] * wv[q];
            const int idx = gi * 32 + cc;
            rv[idx >> 3][idx & 7] = f2bf(s);
        }
    }
    unsigned short* dst = Mt + (size_t)bt * (FF * CCH) + (size_t)f * CCH + j * 64;
    #pragma unroll
    for (int s = 0; s < 8; ++s)
        *reinterpret_cast<u16x8*>(dst + s * 8) = rv[s];   // 128 B/thread contiguous
}

// ---------------- Phase 2: tiled MFMA GEMM, 128 rows x 64 f per block ----------------
__global__ __launch_bounds__(256, 4) void gemm_tile_kernel(
        const float* __restrict__ E, const unsigned short* __restrict__ Mt,
        const float* __restrict__ bias, float* __restrict__ O) {
    const int id0 = blockIdx.x;                       // 0..4095
    const int id  = ((id0 & 7) << 9) | (id0 >> 3);    // XCD-chunked bijection
    const int bt = id >> 5;                           // ids per bt = 32 (L2 window)
    const int fq = (id >> 3) & 3;                     // 64-f slice
    const int rg = id & 7;                            // 128-row group
    const int tid = threadIdx.x;
    const int lane = tid & 63, wq = tid >> 6;
    const int lr5 = lane & 31, kgr = lane >> 5;

    const float*          Ebt = E  + (size_t)bt * (HW * CCH);
    const unsigned short* Mtb = Mt + (size_t)bt * (FF * CCH) + (size_t)(fq * 64) * CCH;
    float*                Obt = O  + (size_t)bt * (HW * FF);

    __shared__ __align__(16) unsigned short Bs[64 * 256];   // 32 KB M-slice, swizzled
    __shared__ __align__(16) unsigned short Et[4][32 * 32]; // 4 x 2KB wave-private tiles

    // ---- stage Bs: linear LDS dest, XOR on the GLOBAL source (rule #21) ----
    #pragma unroll
    for (int p = 0; p < 8; ++p) {
        const int g = p * 256 + tid;                  // 16B granule index
        const int r = g >> 5, s = g & 31;             // f-row, slot
        gload_lds16(Mtb + (size_t)r * CCH + ((s ^ (r & 7)) * 8), &Bs[g * 8]);
    }
    __syncthreads();

    // ---- R7 main loop (verbatim), 1 chunk of 32 rows per wave, 8 k-steps ----
    const int rowbase = rg * 128 + wq * 32;

    const float bv0 = bias[fq * 64 + lr5];
    const float bv1 = bias[fq * 64 + 32 + lr5];

    const int g_r8 = lane >> 3;                       // staging row-in-8
    const int g_s3 = lane & 7;                        // staging 16B slot
    const int bswz = lr5 & 7;                         // Bs read swizzle
    const int eswz = lr5 & 3;                         // E-tile read swizzle
    const unsigned short* Bs0 = &Bs[lr5 * 256];
    const unsigned short* Bs1 = &Bs[(32 + lr5) * 256];
    unsigned short* Etw = &Et[wq][0];
    const unsigned short* Etr = &Etw[lr5 * 32];

    f32x4 Sva[4], Svb[4];
    f32x16 acc0, acc1;

    auto GLOAD = [&](int it, f32x4 (&S)[4]) {         // full 128B-line loads
        const float* base = Ebt + (size_t)rowbase * CCH + (it & 7) * 32 + g_s3 * 4;
        #pragma unroll
        for (int i = 0; i < 4; ++i)
            S[i] = *reinterpret_cast<const f32x4*>(base + (size_t)(i * 8 + g_r8) * CCH);
    };
    auto EWRITE = [&](const f32x4 (&S)[4]) {          // cvt + swizzled ds_write_b64
        #pragma unroll
        for (int i = 0; i < 4; ++i) {
            const int r = i * 8 + g_r8;
            u16x4 h = { f2bf(S[i][0]), f2bf(S[i][1]), f2bf(S[i][2]), f2bf(S[i][3]) };
            *reinterpret_cast<u16x4*>(
                &Etw[r * 32 + (((g_s3 >> 1) ^ (r & 3)) * 8) + (g_s3 & 1) * 4]) = h;
        }
    };
    auto COMPUTE = [&](int it) {
        const int kc = it & 7;
        if (kc == 0) { acc0 = (f32x16)0.f; acc1 = (f32x16)0.f; }
        #pragma unroll
        for (int kk = 0; kk < 2; ++kk) {
            const bf16x8 af = *reinterpret_cast<const bf16x8*>(
                &Etr[((kk * 2 + kgr) ^ eswz) * 8]);
            const bf16x8 b0 = *reinterpret_cast<const bf16x8*>(
                &Bs0[((kc * 4 + kk * 2 + kgr) ^ bswz) * 8]);
            const bf16x8 b1 = *reinterpret_cast<const bf16x8*>(
                &Bs1[((kc * 4 + kk * 2 + kgr) ^ bswz) * 8]);
            acc0 = __builtin_amdgcn_mfma_f32_32x32x16_bf16(af, b0, acc0, 0, 0, 0);
            acc1 = __builtin_amdgcn_mfma_f32_32x32x16_bf16(af, b1, acc1, 0, 0, 0);
        }
        if (kc == 7) {
            // C/D: col = lane&31, row = (reg&3) + 8*(reg>>2) + 4*(lane>>5)
            const int row0 = rowbase + 4 * kgr;
            #pragma unroll
            for (int reg = 0; reg < 16; ++reg) {
                const int r = row0 + (reg & 3) + 8 * (reg >> 2);
                float* op = Obt + (size_t)r * FF + fq * 64 + lr5;
                __builtin_nontemporal_store(fmaxf(acc0[reg] + bv0, 0.f), op);
                __builtin_nontemporal_store(fmaxf(acc1[reg] + bv1, 0.f), op + 32);
            }
        }
    };

    GLOAD(0, Sva);
    GLOAD(1, Svb);
    EWRITE(Sva);                      // tile <- it 0
    for (int itp = 0; itp < 8; itp += 2) {
        COMPUTE(itp);                 // reads tile(itp)
        if (itp + 2 < 8) GLOAD(itp + 2, Sva);
        EWRITE(Svb);                  // tile <- itp+1 (after reads of itp)
        COMPUTE(itp + 1);
        if (itp + 3 < 8) GLOAD(itp + 3, Svb);
        if (itp + 2 < 8) EWRITE(Sva); // tile <- itp+2
    }
}

extern "C" void kernel_launch(void* const* d_in, const int* in_sizes, int n_in,
                              void* d_out, int out_size, void* d_ws, size_t ws_size,
                              hipStream_t stream) {
    const float* dec  = (const float*)d_in[0];   // (8, 256, 256)
    const float* enc  = (const float*)d_in[1];   // (8, 16, 32, 32, 256)
    const float* W    = (const float*)d_in[2];   // (128, 256)
    const float* bias = (const float*)d_in[3];   // (256,)
    float* out = (float*)d_out;                  // (8, 16, 32, 32, 256) fp32
    unsigned short* Mt = (unsigned short*)d_ws;  // 128*256*256*2 = 16.8 MB bf16

    compute_Mt_kernel<<<dim3(4, 128), dim3(256), 0, stream>>>(dec, W, Mt);
    gemm_tile_kernel<<<dim3(4096), dim3(256), 0, stream>>>(enc, Mt, bias, out);
}

// Round 10
// 59.693 us; speedup vs baseline: 1.0507x; 1.0255x over previous
//
#include <hip/hip_runtime.h>

// AttnMap (algebra verified rounds 1-9):
//   Mt[bt][f][ch] = sum_q dec[b, q*16+t, ch] * W[q*8 + (ch>>5)][f]
//   out[bt][s][f] = relu( sum_ch enc[bt][s][ch] * Mt[f][ch] + bias[f] )
// R10: 8-wave (512-thr) gemm blocks sharing one 32KB Bs slice ->
// LDS 48KB/block, 3 blocks/CU = 24 waves/CU (75% occ ceiling, was 50%).
// Per-wave main loop / swizzles / epilogue = R7/R9 verbatim.

#define CCH 256
#define FF  256
#define HW  1024

typedef __bf16 bf16x8 __attribute__((ext_vector_type(8)));
typedef float  f32x4  __attribute__((ext_vector_type(4)));
typedef float  f32x16 __attribute__((ext_vector_type(16)));
typedef unsigned short u16x4 __attribute__((ext_vector_type(4)));
typedef unsigned short u16x8 __attribute__((ext_vector_type(8)));

__device__ __forceinline__ unsigned short f2bf(float f) {
    __bf16 b = (__bf16)f;
    return __builtin_bit_cast(unsigned short, b);
}

__device__ __forceinline__ void gload_lds16(const unsigned short* g, unsigned short* l) {
    __builtin_amdgcn_global_load_lds(
        (const __attribute__((address_space(1))) unsigned int*)g,
        (__attribute__((address_space(3))) unsigned int*)l, 16, 0, 0);
}

// ---------------- Phase 1: Mt[bt][f][ch] (bf16, f-major) — verified R5 ----------------
__global__ __launch_bounds__(256) void compute_Mt_kernel(
        const float* __restrict__ dec, const float* __restrict__ W,
        unsigned short* __restrict__ Mt) {
    const int j  = blockIdx.x;            // g-pair: g = 2j, 2j+1
    const int bt = blockIdx.y;
    const int b  = bt >> 4, t = bt & 15;
    const int f  = threadIdx.x;
    __shared__ float ldec[16][64];        // 16 q x 64 ch (this g-pair)

    const float* decbt = dec + (size_t)b * 65536 + (size_t)t * 256 + j * 64;
    {
        const int q = threadIdx.x >> 4, seg = threadIdx.x & 15;
        const float4 v = *reinterpret_cast<const float4*>(decbt + q * 4096 + seg * 4);
        *reinterpret_cast<float4*>(&ldec[q][seg * 4]) = v;
    }
    __syncthreads();

    u16x8 rv[8];
    #pragma unroll
    for (int gi = 0; gi < 2; ++gi) {
        const int g = j * 2 + gi;
        float wv[16];
        #pragma unroll
        for (int q = 0; q < 16; ++q) wv[q] = W[(q * 8 + g) * FF + f];   // coalesced
        #pragma unroll
        for (int cc = 0; cc < 32; ++cc) {
            float s = 0.f;
            #pragma unroll
            for (int q = 0; q < 16; ++q) s += ldec[q][gi * 32 + cc] * wv[q];
            const int idx = gi * 32 + cc;
            rv[idx >> 3][idx & 7] = f2bf(s);
        }
    }
    unsigned short* dst = Mt + (size_t)bt * (FF * CCH) + (size_t)f * CCH + j * 64;
    #pragma unroll
    for (int s = 0; s < 8; ++s)
        *reinterpret_cast<u16x8*>(dst + s * 8) = rv[s];   // 128 B/thread contiguous
}

// ---------------- Phase 2: tiled MFMA GEMM, 256 rows x 64 f per block ----------------
// 2048 blocks x 512 thr (8 waves). Each wave: 32 rows x 64 f, 8 k-steps.
__global__ __launch_bounds__(512, 6) void gemm_tile_kernel(
        const float* __restrict__ E, const unsigned short* __restrict__ Mt,
        const float* __restrict__ bias, float* __restrict__ O) {
    const int id0 = blockIdx.x;                       // 0..2047
    const int id  = ((id0 & 7) << 8) | (id0 >> 3);    // XCD-chunked bijection
    const int bt = id >> 4;                           // 16 ids per bt
    const int fq = (id >> 2) & 3;                     // 64-f slice
    const int rg = id & 3;                            // 256-row group
    const int tid = threadIdx.x;
    const int lane = tid & 63, wq = tid >> 6;         // wq 0..7
    const int lr5 = lane & 31, kgr = lane >> 5;

    const float*          Ebt = E  + (size_t)bt * (HW * CCH);
    const unsigned short* Mtb = Mt + (size_t)bt * (FF * CCH) + (size_t)(fq * 64) * CCH;
    float*                Obt = O  + (size_t)bt * (HW * FF);

    __shared__ __align__(16) unsigned short Bs[64 * 256];   // 32 KB, shared by 8 waves
    __shared__ __align__(16) unsigned short Et[8][32 * 32]; // 8 x 2KB wave-private

    // ---- stage Bs: linear LDS dest, XOR on the GLOBAL source (rule #21) ----
    #pragma unroll
    for (int p = 0; p < 4; ++p) {
        const int g = p * 512 + tid;                  // 16B granule index, 0..2047
        const int r = g >> 5, s = g & 31;             // f-row, slot
        gload_lds16(Mtb + (size_t)r * CCH + ((s ^ (r & 7)) * 8), &Bs[g * 8]);
    }
    __syncthreads();

    // ---- R7 main loop (verbatim per wave), 32 rows, 8 k-steps ----
    const int rowbase = rg * 256 + wq * 32;

    const float bv0 = bias[fq * 64 + lr5];
    const float bv1 = bias[fq * 64 + 32 + lr5];

    const int g_r8 = lane >> 3;                       // staging row-in-8
    const int g_s3 = lane & 7;                        // staging 16B slot
    const int bswz = lr5 & 7;                         // Bs read swizzle
    const int eswz = lr5 & 3;                         // E-tile read swizzle
    const unsigned short* Bs0 = &Bs[lr5 * 256];
    const unsigned short* Bs1 = &Bs[(32 + lr5) * 256];
    unsigned short* Etw = &Et[wq][0];
    const unsigned short* Etr = &Etw[lr5 * 32];

    f32x4 Sva[4], Svb[4];
    f32x16 acc0, acc1;

    auto GLOAD = [&](int it, f32x4 (&S)[4]) {         // full 128B-line loads
        const float* base = Ebt + (size_t)rowbase * CCH + (it & 7) * 32 + g_s3 * 4;
        #pragma unroll
        for (int i = 0; i < 4; ++i)
            S[i] = *reinterpret_cast<const f32x4*>(base + (size_t)(i * 8 + g_r8) * CCH);
    };
    auto EWRITE = [&](const f32x4 (&S)[4]) {          // cvt + swizzled ds_write_b64
        #pragma unroll
        for (int i = 0; i < 4; ++i) {
            const int r = i * 8 + g_r8;
            u16x4 h = { f2bf(S[i][0]), f2bf(S[i][1]), f2bf(S[i][2]), f2bf(S[i][3]) };
            *reinterpret_cast<u16x4*>(
                &Etw[r * 32 + (((g_s3 >> 1) ^ (r & 3)) * 8) + (g_s3 & 1) * 4]) = h;
        }
    };
    auto COMPUTE = [&](int it) {
        const int kc = it & 7;
        if (kc == 0) { acc0 = (f32x16)0.f; acc1 = (f32x16)0.f; }
        #pragma unroll
        for (int kk = 0; kk < 2; ++kk) {
            const bf16x8 af = *reinterpret_cast<const bf16x8*>(
                &Etr[((kk * 2 + kgr) ^ eswz) * 8]);
            const bf16x8 b0 = *reinterpret_cast<const bf16x8*>(
                &Bs0[((kc * 4 + kk * 2 + kgr) ^ bswz) * 8]);
            const bf16x8 b1 = *reinterpret_cast<const bf16x8*>(
                &Bs1[((kc * 4 + kk * 2 + kgr) ^ bswz) * 8]);
            acc0 = __builtin_amdgcn_mfma_f32_32x32x16_bf16(af, b0, acc0, 0, 0, 0);
            acc1 = __builtin_amdgcn_mfma_f32_32x32x16_bf16(af, b1, acc1, 0, 0, 0);
        }
        if (kc == 7) {
            // C/D: col = lane&31, row = (reg&3) + 8*(reg>>2) + 4*(lane>>5)
            const int row0 = rowbase + 4 * kgr;
            #pragma unroll
            for (int reg = 0; reg < 16; ++reg) {
                const int r = row0 + (reg & 3) + 8 * (reg >> 2);
                float* op = Obt + (size_t)r * FF + fq * 64 + lr5;
                __builtin_nontemporal_store(fmaxf(acc0[reg] + bv0, 0.f), op);
                __builtin_nontemporal_store(fmaxf(acc1[reg] + bv1, 0.f), op + 32);
            }
        }
    };

    GLOAD(0, Sva);
    GLOAD(1, Svb);
    EWRITE(Sva);                      // tile <- it 0
    for (int itp = 0; itp < 8; itp += 2) {
        COMPUTE(itp);                 // reads tile(itp)
        if (itp + 2 < 8) GLOAD(itp + 2, Sva);
        EWRITE(Svb);                  // tile <- itp+1 (after reads of itp)
        COMPUTE(itp + 1);
        if (itp + 3 < 8) GLOAD(itp + 3, Svb);
        if (itp + 2 < 8) EWRITE(Sva); // tile <- itp+2
    }
}

extern "C" void kernel_launch(void* const* d_in, const int* in_sizes, int n_in,
                              void* d_out, int out_size, void* d_ws, size_t ws_size,
                              hipStream_t stream) {
    const float* dec  = (const float*)d_in[0];   // (8, 256, 256)
    const float* enc  = (const float*)d_in[1];   // (8, 16, 32, 32, 256)
    const float* W    = (const float*)d_in[2];   // (128, 256)
    const float* bias = (const float*)d_in[3];   // (256,)
    float* out = (float*)d_out;                  // (8, 16, 32, 32, 256) fp32
    unsigned short* Mt = (unsigned short*)d_ws;  // 128*256*256*2 = 16.8 MB bf16

    compute_Mt_kernel<<<dim3(4, 128), dim3(256), 0, stream>>>(dec, W, Mt);
    gemm_tile_kernel<<<dim3(2048), dim3(512), 0, stream>>>(enc, Mt, bias, out);
}

// Round 11
// 58.260 us; speedup vs baseline: 1.0765x; 1.0246x over previous
//
#include <hip/hip_runtime.h>

// AttnMap (algebra verified rounds 1-10):
//   Mt[bt][f][ch] = sum_q dec[b, q*16+t, ch] * W[q*8 + (ch>>5)][f]
//   out[bt][s][f] = relu( sum_ch enc[bt][s][ch] * Mt[f][ch] + bias[f] )
// R11: 256 rows x 128 f blocks (8 waves; wave = 32 rows x 128 f).
// Bs = 64KB (128f x 256ch), Et = 16KB -> 80KB LDS = 2 blocks/CU.
// E fq-redundancy halved (4x -> 2x); per-wave MFMA per GLOAD doubled.
// Staging / swizzles / schedule / epilogue = R10 verbatim.

#define CCH 256
#define FF  256
#define HW  1024

typedef __bf16 bf16x8 __attribute__((ext_vector_type(8)));
typedef float  f32x4  __attribute__((ext_vector_type(4)));
typedef float  f32x16 __attribute__((ext_vector_type(16)));
typedef unsigned short u16x4 __attribute__((ext_vector_type(4)));
typedef unsigned short u16x8 __attribute__((ext_vector_type(8)));

__device__ __forceinline__ unsigned short f2bf(float f) {
    __bf16 b = (__bf16)f;
    return __builtin_bit_cast(unsigned short, b);
}

__device__ __forceinline__ void gload_lds16(const unsigned short* g, unsigned short* l) {
    __builtin_amdgcn_global_load_lds(
        (const __attribute__((address_space(1))) unsigned int*)g,
        (__attribute__((address_space(3))) unsigned int*)l, 16, 0, 0);
}

// ---------------- Phase 1: Mt[bt][f][ch] (bf16, f-major) — verified R5 ----------------
__global__ __launch_bounds__(256) void compute_Mt_kernel(
        const float* __restrict__ dec, const float* __restrict__ W,
        unsigned short* __restrict__ Mt) {
    const int j  = blockIdx.x;            // g-pair: g = 2j, 2j+1
    const int bt = blockIdx.y;
    const int b  = bt >> 4, t = bt & 15;
    const int f  = threadIdx.x;
    __shared__ float ldec[16][64];        // 16 q x 64 ch (this g-pair)

    const float* decbt = dec + (size_t)b * 65536 + (size_t)t * 256 + j * 64;
    {
        const int q = threadIdx.x >> 4, seg = threadIdx.x & 15;
        const float4 v = *reinterpret_cast<const float4*>(decbt + q * 4096 + seg * 4);
        *reinterpret_cast<float4*>(&ldec[q][seg * 4]) = v;
    }
    __syncthreads();

    u16x8 rv[8];
    #pragma unroll
    for (int gi = 0; gi < 2; ++gi) {
        const int g = j * 2 + gi;
        float wv[16];
        #pragma unroll
        for (int q = 0; q < 16; ++q) wv[q] = W[(q * 8 + g) * FF + f];   // coalesced
        #pragma unroll
        for (int cc = 0; cc < 32; ++cc) {
            float s = 0.f;
            #pragma unroll
            for (int q = 0; q < 16; ++q) s += ldec[q][gi * 32 + cc] * wv[q];
            const int idx = gi * 32 + cc;
            rv[idx >> 3][idx & 7] = f2bf(s);
        }
    }
    unsigned short* dst = Mt + (size_t)bt * (FF * CCH) + (size_t)f * CCH + j * 64;
    #pragma unroll
    for (int s = 0; s < 8; ++s)
        *reinterpret_cast<u16x8*>(dst + s * 8) = rv[s];   // 128 B/thread contiguous
}

// ---------------- Phase 2: tiled MFMA GEMM, 256 rows x 128 f per block ----------------
// 1024 blocks x 512 thr (8 waves). Each wave: 32 rows x 128 f, 8 k-steps.
__global__ __launch_bounds__(512, 4) void gemm_tile_kernel(
        const float* __restrict__ E, const unsigned short* __restrict__ Mt,
        const float* __restrict__ bias, float* __restrict__ O) {
    const int id0 = blockIdx.x;                       // 0..1023
    const int id  = ((id0 & 7) << 7) | (id0 >> 3);    // XCD-chunked bijection
    const int bt = id >> 3;                           // 8 ids per bt
    const int fh = (id >> 2) & 1;                     // 128-f half
    const int rg = id & 3;                            // 256-row group
    const int tid = threadIdx.x;
    const int lane = tid & 63, wq = tid >> 6;         // wq 0..7
    const int lr5 = lane & 31, kgr = lane >> 5;

    const float*          Ebt = E  + (size_t)bt * (HW * CCH);
    const unsigned short* Mtb = Mt + (size_t)bt * (FF * CCH) + (size_t)(fh * 128) * CCH;
    float*                Obt = O  + (size_t)bt * (HW * FF);

    __shared__ __align__(16) unsigned short Bs[128 * 256];  // 64 KB, shared by 8 waves
    __shared__ __align__(16) unsigned short Et[8][32 * 32]; // 8 x 2KB wave-private

    // ---- stage Bs: linear LDS dest, XOR on the GLOBAL source (rule #21) ----
    #pragma unroll
    for (int p = 0; p < 8; ++p) {
        const int g = p * 512 + tid;                  // 16B granule index, 0..4095
        const int r = g >> 5, s = g & 31;             // f-row, slot
        gload_lds16(Mtb + (size_t)r * CCH + ((s ^ (r & 7)) * 8), &Bs[g * 8]);
    }
    __syncthreads();

    // ---- main loop (R10 schedule), 32 rows/wave, 8 k-steps, 4 fn ----
    const int rowbase = rg * 256 + wq * 32;

    float bv[4];
    #pragma unroll
    for (int fn = 0; fn < 4; ++fn) bv[fn] = bias[fh * 128 + fn * 32 + lr5];

    const int g_r8 = lane >> 3;                       // staging row-in-8
    const int g_s3 = lane & 7;                        // staging 16B slot
    const int bswz = lr5 & 7;                         // Bs read swizzle
    const int eswz = lr5 & 3;                         // E-tile read swizzle
    const unsigned short* Bsp[4];
    #pragma unroll
    for (int fn = 0; fn < 4; ++fn) Bsp[fn] = &Bs[(fn * 32 + lr5) * 256];
    unsigned short* Etw = &Et[wq][0];
    const unsigned short* Etr = &Etw[lr5 * 32];

    f32x4 Sva[4], Svb[4];
    f32x16 acc0, acc1, acc2, acc3;

    auto GLOAD = [&](int it, f32x4 (&S)[4]) {         // full 128B-line loads
        const float* base = Ebt + (size_t)rowbase * CCH + (it & 7) * 32 + g_s3 * 4;
        #pragma unroll
        for (int i = 0; i < 4; ++i)
            S[i] = *reinterpret_cast<const f32x4*>(base + (size_t)(i * 8 + g_r8) * CCH);
    };
    auto EWRITE = [&](const f32x4 (&S)[4]) {          // cvt + swizzled ds_write_b64
        #pragma unroll
        for (int i = 0; i < 4; ++i) {
            const int r = i * 8 + g_r8;
            u16x4 h = { f2bf(S[i][0]), f2bf(S[i][1]), f2bf(S[i][2]), f2bf(S[i][3]) };
            *reinterpret_cast<u16x4*>(
                &Etw[r * 32 + (((g_s3 >> 1) ^ (r & 3)) * 8) + (g_s3 & 1) * 4]) = h;
        }
    };
    auto COMPUTE = [&](int it) {
        const int kc = it & 7;
        if (kc == 0) {
            acc0 = (f32x16)0.f; acc1 = (f32x16)0.f;
            acc2 = (f32x16)0.f; acc3 = (f32x16)0.f;
        }
        #pragma unroll
        for (int kk = 0; kk < 2; ++kk) {
            const bf16x8 af = *reinterpret_cast<const bf16x8*>(
                &Etr[((kk * 2 + kgr) ^ eswz) * 8]);
            const int bo = ((kc * 4 + kk * 2 + kgr) ^ bswz) * 8;
            acc0 = __builtin_amdgcn_mfma_f32_32x32x16_bf16(
                af, *reinterpret_cast<const bf16x8*>(&Bsp[0][bo]), acc0, 0, 0, 0);
            acc1 = __builtin_amdgcn_mfma_f32_32x32x16_bf16(
                af, *reinterpret_cast<const bf16x8*>(&Bsp[1][bo]), acc1, 0, 0, 0);
            acc2 = __builtin_amdgcn_mfma_f32_32x32x16_bf16(
                af, *reinterpret_cast<const bf16x8*>(&Bsp[2][bo]), acc2, 0, 0, 0);
            acc3 = __builtin_amdgcn_mfma_f32_32x32x16_bf16(
                af, *reinterpret_cast<const bf16x8*>(&Bsp[3][bo]), acc3, 0, 0, 0);
        }
        if (kc == 7) {
            // C/D: col = lane&31, row = (reg&3) + 8*(reg>>2) + 4*(lane>>5)
            const int row0 = rowbase + 4 * kgr;
            #pragma unroll
            for (int reg = 0; reg < 16; ++reg) {
                const int r = row0 + (reg & 3) + 8 * (reg >> 2);
                float* op = Obt + (size_t)r * FF + fh * 128 + lr5;
                __builtin_nontemporal_store(fmaxf(acc0[reg] + bv[0], 0.f), op);
                __builtin_nontemporal_store(fmaxf(acc1[reg] + bv[1], 0.f), op + 32);
                __builtin_nontemporal_store(fmaxf(acc2[reg] + bv[2], 0.f), op + 64);
                __builtin_nontemporal_store(fmaxf(acc3[reg] + bv[3], 0.f), op + 96);
            }
        }
    };

    GLOAD(0, Sva);
    GLOAD(1, Svb);
    EWRITE(Sva);                      // tile <- it 0
    for (int itp = 0; itp < 8; itp += 2) {
        COMPUTE(itp);                 // reads tile(itp)
        if (itp + 2 < 8) GLOAD(itp + 2, Sva);
        EWRITE(Svb);                  // tile <- itp+1 (after reads of itp)
        COMPUTE(itp + 1);
        if (itp + 3 < 8) GLOAD(itp + 3, Svb);
        if (itp + 2 < 8) EWRITE(Sva); // tile <- itp+2
    }
}

extern "C" void kernel_launch(void* const* d_in, const int* in_sizes, int n_in,
                              void* d_out, int out_size, void* d_ws, size_t ws_size,
                              hipStream_t stream) {
    const float* dec  = (const float*)d_in[0];   // (8, 256, 256)
    const float* enc  = (const float*)d_in[1];   // (8, 16, 32, 32, 256)
    const float* W    = (const float*)d_in[2];   // (128, 256)
    const float* bias = (const float*)d_in[3];   // (256,)
    float* out = (float*)d_out;                  // (8, 16, 32, 32, 256) fp32
    unsigned short* Mt = (unsigned short*)d_ws;  // 128*256*256*2 = 16.8 MB bf16

    compute_Mt_kernel<<<dim3(4, 128), dim3(256), 0, stream>>>(dec, W, Mt);
    gemm_tile_kernel<<<dim3(1024), dim3(512), 0, stream>>>(enc, Mt, bias, out);
}